// Round 8
// baseline (339.828 us; speedup 1.0000x reference)
//
#include <hip/hip_runtime.h>
#include <cfloat>
#include <cmath>
#include <cstdint>

#define NPT   1024          // points per cloud
#define NCL   32            // clouds (B*S)
#define PTOT  32768         // total points
#define HH    64
#define KNN_K 16
#define KNN_BLKS (NCL * 256)   // 8192: 4 queries per block

#define RFL(x) __builtin_amdgcn_readfirstlane(x)

__device__ __forceinline__ float wave_sum64(float t) {
#pragma unroll
  for (int o = 32; o > 0; o >>= 1) t += __shfl_xor(t, o, 64);
  return t;
}

// Multi-value butterfly reduction: NV values/lane summed across 64 lanes.
// Lane l ends holding the full sum of value (l & (NV-1)).
template <int NV>
__device__ __forceinline__ float mreduce(const float (&P)[NV], int lane) {
  float buf[NV];
#pragma unroll
  for (int i = 0; i < NV; ++i) buf[i] = P[i];
#pragma unroll
  for (int s = 0; (1 << s) < NV; ++s) {
    bool hi = (lane & (1 << s)) != 0;
#pragma unroll
    for (int m = 0; m < (NV >> (s + 1)); ++m) {
      float a = buf[2 * m], b = buf[2 * m + 1];
      float keep = hi ? b : a;
      float send = hi ? a : b;
      buf[m] = keep + __shfl_xor(send, 1 << s, 64);
    }
  }
  float t = buf[0];
#pragma unroll
  for (int o = NV; o < 64; o <<= 1) t += __shfl_xor(t, o, 64);
  return t;
}

__device__ __forceinline__ float gelu_f(float z) {
  float zc = 0.7978845608028654f * (z + 0.044715f * z * z * z);
  float t = __expf(2.0f * zc);
  float th = 1.0f - 2.0f / (t + 1.0f);
  return 0.5f * z * (1.0f + th);
}

// ---------------- K0: fused [knn-select | input projection] ----------------
__global__ __launch_bounds__(256) void k_front(
    const float* __restrict__ pts, const float* __restrict__ w_in,
    const float* __restrict__ b_in, float* __restrict__ x,
    float* __restrict__ pos4, int* __restrict__ nidx) {
  if (blockIdx.x >= KNN_BLKS) {
    // ---- input projection role ----
    int p = (blockIdx.x - KNN_BLKS) * 4 + (threadIdx.x >> 6);
    int h = threadIdx.x & 63;
    const float* pp = pts + p * 6;
    float acc = b_in[h];
#pragma unroll
    for (int f = 0; f < 6; ++f) acc += pp[f] * w_in[f * HH + h];
    x[p * HH + h] = acc;
    if (h < 4) pos4[p * 4 + h] = (h < 3) ? pp[h] : 0.0f;
    return;
  }

  // ---- knn role: 4 queries (one per wave) ----
  __shared__ float sx[NPT], sy[NPT], sz[NPT];
  int cloud = blockIdx.x >> 8;
  int qbase = (blockIdx.x & 255) * 4;
  const float* cp = pts + (size_t)cloud * NPT * 6;
  for (int j = threadIdx.x; j < NPT; j += 256) {
    sx[j] = cp[j * 6 + 0];
    sy[j] = cp[j * 6 + 1];
    sz[j] = cp[j * 6 + 2];
  }
  __syncthreads();

  int wv = threadIdx.x >> 6;
  int lane = threadIdx.x & 63;
  int i = qbase + wv;
  float qx = sx[i], qy = sy[i], qz = sz[i];

  // d2 >= 0 -> float bits are order-isomorphic to u32
  unsigned du[16];
#pragma unroll
  for (int c = 0; c < 16; ++c) {
    int j = c * 64 + lane;
    float dx = qx - sx[j], dy = qy - sy[j], dz = qz - sz[j];
    // exact IEEE, reference order, no fma contraction
    float d2 = __fadd_rn(__fadd_rn(__fmul_rn(dx, dx), __fmul_rn(dy, dy)),
                         __fmul_rn(dz, dz));
    du[c] = __float_as_uint(d2);
  }

  // coarse greedy MSB->bit15: t = max 2^15-aligned value with count(<t) <= 15
  unsigned t = 0u;
#pragma unroll
  for (int bit = 30; bit >= 15; --bit) {
    unsigned tp = t | (1u << bit);
    int cnt = 0;
#pragma unroll
    for (int c = 0; c < 16; ++c)
      cnt += __popcll(__ballot(du[c] < tp));
    if (cnt <= 15) t = tp;
  }
  // 16th value lies in [t, t + 2^15)

  // collect strict-less survivors (count r <= 15), slots via ballot prefix
  int obase = (cloud * NPT + i) * KNN_K;
  unsigned long long below = (1ull << lane) - 1ull;
  int slot = 0;
#pragma unroll
  for (int c = 0; c < 16; ++c) {
    bool lt = du[c] < t;
    unsigned long long m = __ballot(lt);
    if (lt) {
      int off = __popcll(m & below);
      nidx[obase + slot + off] = c * 64 + lane;
    }
    slot += __popcll(m);
  }

  // exact tail: extract (16 - slot) smallest from the boundary bucket,
  // ties broken by lowest global index (lax.top_k stable semantics)
  int erem = KNN_K - slot;
  unsigned hi_end = t + (1u << 15);
  unsigned bu[16];
#pragma unroll
  for (int c = 0; c < 16; ++c)
    bu[c] = (du[c] >= t && du[c] < hi_end) ? du[c] : 0xFFFFFFFFu;
  for (int r2 = 0; r2 < erem; ++r2) {
    unsigned bd = bu[0];
    int bc = 0;
#pragma unroll
    for (int c = 1; c < 16; ++c) {
      if (bu[c] < bd) { bd = bu[c]; bc = c; }   // strict -> lowest c on tie
    }
    unsigned gd = bd;
#pragma unroll
    for (int o = 32; o > 0; o >>= 1) {
      unsigned g2 = (unsigned)__shfl_xor((int)gd, o, 64);
      gd = (g2 < gd) ? g2 : gd;
    }
    int myidx = bc * 64 + lane;
    int gidx = (bd == gd) ? myidx : 0x7fffffff;
#pragma unroll
    for (int o = 32; o > 0; o >>= 1) {
      int g2 = __shfl_xor(gidx, o, 64);
      gidx = (g2 < gidx) ? g2 : gidx;
    }
    if (lane == 0) nidx[obase + slot + r2] = gidx;
    int sel = (myidx == gidx) ? bc : 99;
#pragma unroll
    for (int c = 0; c < 16; ++c) bu[c] = (c == sel) ? 0xFFFFFFFFu : bu[c];
  }
}

// ---------------- K2: register-tiled qkv GEMM (4 pts/wave) ------------------
__global__ __launch_bounds__(256) void k_qkv_gemm(
    const float* __restrict__ x, const float* __restrict__ pos4,
    const float* __restrict__ Wq, const float* __restrict__ bq,
    const float* __restrict__ Wk, const float* __restrict__ bk,
    const float* __restrict__ Wv, const float* __restrict__ bv,
    const float* __restrict__ Wpe, const float* __restrict__ bpe,
    const float* __restrict__ Wpd, const float* __restrict__ bpd,
    float* __restrict__ qq, float* __restrict__ kkv) {
  int lane = threadIdx.x & 63;
  int pb = RFL(blockIdx.x * 16 + (threadIdx.x >> 6) * 4);
  const float* xw = x + (size_t)pb * HH;
  const float4* posw = reinterpret_cast<const float4*>(pos4) + pb;

  float wpe0 = Wpe[lane], wpe1 = Wpe[HH + lane], wpe2 = Wpe[2 * HH + lane];
  float wpd0 = Wpd[lane], wpd1 = Wpd[HH + lane], wpd2 = Wpd[2 * HH + lane];
  float we0 = wpe0 + wpd0, we1 = wpe1 + wpd1, we2 = wpe2 + wpd2;
  float bqq = bq[lane] + bpe[lane];
  float bkk = bk[lane] + bpe[lane] + bpd[lane];
  float bvv = bv[lane];

  float aq[4], ak[4], av[4];
#pragma unroll
  for (int p = 0; p < 4; ++p) { aq[p] = bqq; ak[p] = bkk; av[p] = bvv; }

#pragma unroll
  for (int c = 0; c < 8; ++c) {
    float wq8[8], wk8[8], wv8[8];
#pragma unroll
    for (int j = 0; j < 8; ++j) {
      int g = c * 8 + j;
      wq8[j] = Wq[g * HH + lane];
      wk8[j] = Wk[g * HH + lane];
      wv8[j] = Wv[g * HH + lane];
    }
#pragma unroll
    for (int p = 0; p < 4; ++p) {
#pragma unroll
      for (int j = 0; j < 8; ++j) {
        float xv = xw[p * HH + c * 8 + j];   // wave-uniform -> scalar load
        aq[p] = fmaf(xv, wq8[j], aq[p]);
        ak[p] = fmaf(xv, wk8[j], ak[p]);
        av[p] = fmaf(xv, wv8[j], av[p]);
      }
    }
  }

#pragma unroll
  for (int p = 0; p < 4; ++p) {
    float4 pp = posw[p];
    float qv = aq[p] + pp.x * wpe0 + pp.y * wpe1 + pp.z * wpe2;
    float kv = ak[p] + pp.x * we0 + pp.y * we1 + pp.z * we2;
    qq[(size_t)(pb + p) * HH + lane] = qv;
    reinterpret_cast<float2*>(kkv + ((size_t)(pb + p) << 7))[lane] =
        make_float2(kv, av[p]);
  }
}

// ---------------- K3: FUSED attn + Wo + gelu + residual + LN (+pool) --------
// 4 points/wave. Attention output lives in-wave (lane = feature), so the
// Wo matvec runs via v_readlane broadcasts -- no global roundtrip.
__global__ __launch_bounds__(256) void k_attn_wo(
    const float* __restrict__ qq, const float* __restrict__ kkv,
    const int* __restrict__ nidx, const float* __restrict__ pos4,
    const float* __restrict__ Wpd, const float* __restrict__ Wa,
    const float* __restrict__ ba,
    const float* __restrict__ Wo, const float* __restrict__ bo,
    float* __restrict__ x,
    const float* __restrict__ ln_s, const float* __restrict__ ln_b,
    float* __restrict__ partial, int do_pool) {
  __shared__ float red[4][HH];
  int lane = threadIdx.x & 63;
  int wv = threadIdx.x >> 6;
  int bid = blockIdx.x;
  int vb = (bid & 7) * (2048 / 8) + (bid >> 3);   // XCD-chunked remap
  int pb = RFL(vb * 16 + wv * 4);
  int cbase = pb & ~(NPT - 1);

  float wa = Wa[lane];
  float wpd0 = Wpd[lane], wpd1 = Wpd[HH + lane], wpd2 = Wpd[2 * HH + lane];
  float ba0 = ba[0];

  float out[4];
#pragma unroll
  for (int p = 0; p < 4; ++p) {
    int pu = pb + p;
    float4 pp = reinterpret_cast<const float4*>(pos4)[pu];
    float u = qq[(size_t)pu * HH + lane] * wa * 0.125f;
    float pdq = pp.x * wpd0 + pp.y * wpd1 + pp.z * wpd2;
    float C0 = wave_sum64(u * pdq) - ba0;

    const int4* niw = reinterpret_cast<const int4*>(nidx + (size_t)pu * KNN_K);
    int nj[KNN_K];
#pragma unroll
    for (int g = 0; g < 4; ++g) {
      int4 r = niw[g];
      nj[g * 4 + 0] = r.x; nj[g * 4 + 1] = r.y;
      nj[g * 4 + 2] = r.z; nj[g * 4 + 3] = r.w;
    }

    float vj[KNN_K], P[KNN_K];
#pragma unroll
    for (int jj = 0; jj < KNN_K; ++jj) {
      float2 kv = reinterpret_cast<const float2*>(
          kkv + ((size_t)(cbase + nj[jj]) << 7))[lane];
      vj[jj] = kv.y;
      P[jj] = u * kv.x;
    }

    // lane l holds full logit for jj = l & 15
    float T = mreduce<16>(P, lane);
    float lg = T - C0;

    float mx = lg;
#pragma unroll
    for (int o = 1; o < 16; o <<= 1) mx = fmaxf(mx, __shfl_xor(mx, o, 64));
    float e = __expf(lg - mx);
    float s = e;
#pragma unroll
    for (int o = 1; o < 16; o <<= 1) s += __shfl_xor(s, o, 64);

    float oacc = 0.f;
    int sb = lane & 48;
#pragma unroll
    for (int jj = 0; jj < KNN_K; ++jj)
      oacc = fmaf(__shfl(e, sb | jj, 64), vj[jj], oacc);

    out[p] = oacc / s;
  }

  // ---- Wo matvec in-wave: acc[p][lane] += out[p][g] * Wo[g][lane] ----
  float acc[4];
  float b0 = bo[lane];
#pragma unroll
  for (int p = 0; p < 4; ++p) acc[p] = b0;

#pragma unroll
  for (int c = 0; c < 8; ++c) {
    float w8[8];
#pragma unroll
    for (int j = 0; j < 8; ++j) w8[j] = Wo[(c * 8 + j) * HH + lane];
#pragma unroll
    for (int p = 0; p < 4; ++p) {
#pragma unroll
      for (int j = 0; j < 8; ++j) {
        float og = __shfl(out[p], c * 8 + j, 64);  // const lane -> v_readlane
        acc[p] = fmaf(og, w8[j], acc[p]);
      }
    }
  }

  float sg = ln_s[lane], bg = ln_b[lane];
  float xn[4];
#pragma unroll
  for (int p = 0; p < 4; ++p)
    xn[p] = x[(size_t)(pb + p) * HH + lane] + gelu_f(acc[p]);

  float Ts = mreduce<4>(xn, lane);
  float dd[4], sq[4];
#pragma unroll
  for (int p = 0; p < 4; ++p) {
    float mu = __shfl(Ts, p, 64) * (1.0f / HH);
    dd[p] = xn[p] - mu;
    sq[p] = dd[p] * dd[p];
  }
  float Tv = mreduce<4>(sq, lane);
  float mxp = -FLT_MAX;
#pragma unroll
  for (int p = 0; p < 4; ++p) {
    float var = __shfl(Tv, p, 64) * (1.0f / HH);
    float yv = dd[p] * rsqrtf(var + 1e-6f) * sg + bg;
    x[(size_t)(pb + p) * HH + lane] = yv;
    mxp = fmaxf(mxp, yv);
  }

  if (do_pool) {   // last layer: per-vblock (16-point) partial max
    red[wv][lane] = mxp;
    __syncthreads();
    if (wv == 0) {
      float m = fmaxf(fmaxf(red[0][lane], red[1][lane]),
                      fmaxf(red[2][lane], red[3][lane]));
      partial[(size_t)vb * HH + lane] = m;   // indexed by VIRTUAL block
    }
  }
}

// ---------------- K6: fused pool-finish + set-encoder + final LN + max ------
__global__ __launch_bounds__(512) void k_enc(
    const float* __restrict__ partial,
    const float* __restrict__ Wek, const float* __restrict__ bek,
    const float* __restrict__ Weq, const float* __restrict__ beq,
    const float* __restrict__ Wev, const float* __restrict__ bev,
    const float* __restrict__ We1, const float* __restrict__ be1,
    const float* __restrict__ We2, const float* __restrict__ be2,
    const float* __restrict__ ln2_s, const float* __restrict__ ln2_b,
    float* __restrict__ out) {
  __shared__ float xs[8][HH], ks[8][HH], vs[8][HH], x2[8][HH];
  int b = blockIdx.x;
  int t = threadIdx.x >> 6;     // token (cloud-in-batch) 0..7
  int h = threadIdx.x & 63;
  {
    int ci = b * 8 + t;
    const float* pp = partial + (size_t)ci * 64 * HH + h;
    float mx = pp[0];
#pragma unroll
    for (int c8 = 1; c8 < 64; ++c8) mx = fmaxf(mx, pp[c8 * HH]);
    xs[t][h] = mx;
  }
  __syncthreads();

  float kk = bek[h], qq = beq[h], vv = bev[h];
#pragma unroll 8
  for (int g = 0; g < HH; ++g) {
    float xv = xs[t][g];
    kk += xv * Wek[g * HH + h];
    qq += xv * Weq[g * HH + h];
    vv += xv * Wev[g * HH + h];
  }
  ks[t][h] = kk;
  vs[t][h] = vv;
  __syncthreads();

  float logit[8];
#pragma unroll
  for (int s = 0; s < 8; ++s) {
    float tt = qq * ks[s][h];
    logit[s] = wave_sum64(tt) * 0.125f;
  }
  float m = logit[0];
#pragma unroll
  for (int s = 1; s < 8; ++s) m = fmaxf(m, logit[s]);
  float ssum = 0.f;
#pragma unroll
  for (int s = 0; s < 8; ++s) { logit[s] = expf(logit[s] - m); ssum += logit[s]; }
  float o = 0.f;
#pragma unroll
  for (int s = 0; s < 8; ++s) o += (logit[s] / ssum) * vs[s][h];

  float h1 = be1[h];
#pragma unroll 8
  for (int g = 0; g < HH; ++g) h1 += __shfl(o, g, 64) * We1[g * HH + h];
  h1 = gelu_f(h1);
  float h2 = be2[h];
#pragma unroll 8
  for (int g = 0; g < HH; ++g) h2 += __shfl(h1, g, 64) * We2[g * HH + h];

  float xn = xs[t][h] + h2;
  float mu = wave_sum64(xn) * (1.0f / HH);
  float d = xn - mu;
  float var = wave_sum64(d * d) * (1.0f / HH);
  float yv = d * rsqrtf(var + 1e-6f) * ln2_s[h] + ln2_b[h];
  x2[t][h] = yv;
  __syncthreads();
  if (t == 0) {
    float mm = x2[0][h];
#pragma unroll
    for (int s = 1; s < 8; ++s) mm = fmaxf(mm, x2[s][h]);
    out[b * HH + h] = mm;
  }
}

// ---------------------------------------------------------------------------
extern "C" void kernel_launch(void* const* d_in, const int* in_sizes, int n_in,
                              void* d_out, int out_size, void* d_ws, size_t ws_size,
                              hipStream_t stream) {
  const float* points = (const float*)d_in[0];
  const float* w_in   = (const float*)d_in[1];
  const float* b_in   = (const float*)d_in[2];
  const float* Wq     = (const float*)d_in[3];
  const float* bq     = (const float*)d_in[4];
  const float* Wk     = (const float*)d_in[5];
  const float* bk     = (const float*)d_in[6];
  const float* Wv     = (const float*)d_in[7];
  const float* bv     = (const float*)d_in[8];
  const float* Wpe    = (const float*)d_in[9];
  const float* bpe    = (const float*)d_in[10];
  const float* Wpd    = (const float*)d_in[11];
  const float* bpd    = (const float*)d_in[12];
  const float* Wa     = (const float*)d_in[13];
  const float* ba     = (const float*)d_in[14];
  const float* Wo     = (const float*)d_in[15];
  const float* bo     = (const float*)d_in[16];
  const float* ln_s   = (const float*)d_in[17];
  const float* ln_b   = (const float*)d_in[18];
  const float* Wek    = (const float*)d_in[19];
  const float* bek    = (const float*)d_in[20];
  const float* Weq    = (const float*)d_in[21];
  const float* beq    = (const float*)d_in[22];
  const float* Wev    = (const float*)d_in[23];
  const float* bev    = (const float*)d_in[24];
  const float* We1    = (const float*)d_in[25];
  const float* be1    = (const float*)d_in[26];
  const float* We2    = (const float*)d_in[27];
  const float* be2    = (const float*)d_in[28];
  const float* ln2_s  = (const float*)d_in[29];
  const float* ln2_b  = (const float*)d_in[30];

  float* ws      = (float*)d_ws;
  float* pos4    = ws;                      // 4*PTOT
  float* xbuf    = pos4 + 4 * PTOT;         // 64*PTOT
  float* qbuf    = xbuf + 64 * PTOT;        // 64*PTOT (qq)
  float* kkv     = qbuf + 64 * PTOT;        // 128*PTOT (kk,v interleaved)
  float* partial = kkv + 128 * PTOT;        // 2048*HH
  int*   nidx    = (int*)(partial + 2048 * HH);  // 16*PTOT ints

  k_front<<<KNN_BLKS + PTOT / 4, 256, 0, stream>>>(points, w_in, b_in,
                                                   xbuf, pos4, nidx);

  for (int l = 0; l < 3; ++l) {
    k_qkv_gemm<<<PTOT / 16, 256, 0, stream>>>(xbuf, pos4,
        Wq + l * HH * HH, bq + l * HH,
        Wk + l * HH * HH, bk + l * HH,
        Wv + l * HH * HH, bv + l * HH,
        Wpe + l * 3 * HH, bpe + l * HH,
        Wpd + l * 3 * HH, bpd + l * HH,
        qbuf, kkv);
    k_attn_wo<<<PTOT / 16, 256, 0, stream>>>(qbuf, kkv, nidx, pos4,
        Wpd + l * 3 * HH, Wa + l * HH, ba + l,
        Wo + l * HH * HH, bo + l * HH, xbuf,
        ln_s + l * HH, ln_b + l * HH, partial, l == 2 ? 1 : 0);
  }

  k_enc<<<4, 512, 0, stream>>>(partial, Wek, bek, Weq, beq, Wev, bev,
                               We1, be1, We2, be2, ln2_s, ln2_b, (float*)d_out);
}

// Round 9
// 217.461 us; speedup vs baseline: 1.5627x; 1.5627x over previous
//
#include <hip/hip_runtime.h>
#include <cfloat>
#include <cmath>
#include <cstdint>

#define NPT   1024          // points per cloud
#define NCL   32            // clouds (B*S)
#define PTOT  32768         // total points
#define HH    64
#define KNN_K 16
#define KNN_BLKS (NCL * 256)   // 8192: 4 queries per block

#define RFL(x) __builtin_amdgcn_readfirstlane(x)

__device__ __forceinline__ float wave_sum64(float t) {
#pragma unroll
  for (int o = 32; o > 0; o >>= 1) t += __shfl_xor(t, o, 64);
  return t;
}

// Multi-value butterfly reduction: NV values/lane summed across 64 lanes.
// Lane l ends holding the full sum of value (l & (NV-1)).
template <int NV>
__device__ __forceinline__ float mreduce(const float (&P)[NV], int lane) {
  float buf[NV];
#pragma unroll
  for (int i = 0; i < NV; ++i) buf[i] = P[i];
#pragma unroll
  for (int s = 0; (1 << s) < NV; ++s) {
    bool hi = (lane & (1 << s)) != 0;
#pragma unroll
    for (int m = 0; m < (NV >> (s + 1)); ++m) {
      float a = buf[2 * m], b = buf[2 * m + 1];
      float keep = hi ? b : a;
      float send = hi ? a : b;
      buf[m] = keep + __shfl_xor(send, 1 << s, 64);
    }
  }
  float t = buf[0];
#pragma unroll
  for (int o = NV; o < 64; o <<= 1) t += __shfl_xor(t, o, 64);
  return t;
}

__device__ __forceinline__ float gelu_f(float z) {
  float zc = 0.7978845608028654f * (z + 0.044715f * z * z * z);
  float t = __expf(2.0f * zc);
  float th = 1.0f - 2.0f / (t + 1.0f);
  return 0.5f * z * (1.0f + th);
}

// ---------------- K0: fused [knn-select | input projection] ----------------
__global__ __launch_bounds__(256) void k_front(
    const float* __restrict__ pts, const float* __restrict__ w_in,
    const float* __restrict__ b_in, float* __restrict__ x,
    float* __restrict__ pos4, int* __restrict__ nidx) {
  if (blockIdx.x >= KNN_BLKS) {
    // ---- input projection role (XCD-chunked so x lands in the right L2) ----
    int b2 = blockIdx.x - KNN_BLKS;                 // [0, 8192)
    int vb = (b2 & 7) * 1024 + (b2 >> 3);
    int p = vb * 4 + (threadIdx.x >> 6);
    int h = threadIdx.x & 63;
    const float* pp = pts + p * 6;
    float acc = b_in[h];
#pragma unroll
    for (int f = 0; f < 6; ++f) acc += pp[f] * w_in[f * HH + h];
    x[p * HH + h] = acc;
    if (h < 4) pos4[p * 4 + h] = (h < 3) ? pp[h] : 0.0f;
    return;
  }

  // ---- knn role: 4 queries (one per wave) ----
  __shared__ float sx[NPT], sy[NPT], sz[NPT];
  int cloud = blockIdx.x >> 8;
  int qbase = (blockIdx.x & 255) * 4;
  const float* cp = pts + (size_t)cloud * NPT * 6;
  for (int j = threadIdx.x; j < NPT; j += 256) {
    sx[j] = cp[j * 6 + 0];
    sy[j] = cp[j * 6 + 1];
    sz[j] = cp[j * 6 + 2];
  }
  __syncthreads();

  int wv = threadIdx.x >> 6;
  int lane = threadIdx.x & 63;
  int i = qbase + wv;
  float qx = sx[i], qy = sy[i], qz = sz[i];

  // d2 >= 0 -> float bits are order-isomorphic to u32
  unsigned du[16];
#pragma unroll
  for (int c = 0; c < 16; ++c) {
    int j = c * 64 + lane;
    float dx = qx - sx[j], dy = qy - sy[j], dz = qz - sz[j];
    // exact IEEE, reference order, no fma contraction
    float d2 = __fadd_rn(__fadd_rn(__fmul_rn(dx, dx), __fmul_rn(dy, dy)),
                         __fmul_rn(dz, dz));
    du[c] = __float_as_uint(d2);
  }

  // coarse greedy MSB->bit15: t = max 2^15-aligned value with count(<t) <= 15
  unsigned t = 0u;
#pragma unroll
  for (int bit = 30; bit >= 15; --bit) {
    unsigned tp = t | (1u << bit);
    int cnt = 0;
#pragma unroll
    for (int c = 0; c < 16; ++c)
      cnt += __popcll(__ballot(du[c] < tp));
    if (cnt <= 15) t = tp;
  }
  // 16th value lies in [t, t + 2^15)

  // collect strict-less survivors (count r <= 15), slots via ballot prefix
  int obase = (cloud * NPT + i) * KNN_K;
  unsigned long long below = (1ull << lane) - 1ull;
  int slot = 0;
#pragma unroll
  for (int c = 0; c < 16; ++c) {
    bool lt = du[c] < t;
    unsigned long long m = __ballot(lt);
    if (lt) {
      int off = __popcll(m & below);
      nidx[obase + slot + off] = c * 64 + lane;
    }
    slot += __popcll(m);
  }

  // exact tail: extract (16 - slot) smallest from the boundary bucket,
  // ties broken by lowest global index (lax.top_k stable semantics)
  int erem = KNN_K - slot;
  unsigned hi_end = t + (1u << 15);
  unsigned bu[16];
#pragma unroll
  for (int c = 0; c < 16; ++c)
    bu[c] = (du[c] >= t && du[c] < hi_end) ? du[c] : 0xFFFFFFFFu;
  for (int r2 = 0; r2 < erem; ++r2) {
    unsigned bd = bu[0];
    int bc = 0;
#pragma unroll
    for (int c = 1; c < 16; ++c) {
      if (bu[c] < bd) { bd = bu[c]; bc = c; }   // strict -> lowest c on tie
    }
    unsigned gd = bd;
#pragma unroll
    for (int o = 32; o > 0; o >>= 1) {
      unsigned g2 = (unsigned)__shfl_xor((int)gd, o, 64);
      gd = (g2 < gd) ? g2 : gd;
    }
    int myidx = bc * 64 + lane;
    int gidx = (bd == gd) ? myidx : 0x7fffffff;
#pragma unroll
    for (int o = 32; o > 0; o >>= 1) {
      int g2 = __shfl_xor(gidx, o, 64);
      gidx = (g2 < gidx) ? g2 : gidx;
    }
    if (lane == 0) nidx[obase + slot + r2] = gidx;
    int sel = (myidx == gidx) ? bc : 99;
#pragma unroll
    for (int c = 0; c < 16; ++c) bu[c] = (c == sel) ? 0xFFFFFFFFu : bu[c];
  }
}

// ---------------- K2: register-tiled qkv GEMM (4 pts/wave, XCD-chunked) -----
__global__ __launch_bounds__(256) void k_qkv_gemm(
    const float* __restrict__ x, const float* __restrict__ pos4,
    const float* __restrict__ Wq, const float* __restrict__ bq,
    const float* __restrict__ Wk, const float* __restrict__ bk,
    const float* __restrict__ Wv, const float* __restrict__ bv,
    const float* __restrict__ Wpe, const float* __restrict__ bpe,
    const float* __restrict__ Wpd, const float* __restrict__ bpd,
    float* __restrict__ qq, float* __restrict__ kkv) {
  int lane = threadIdx.x & 63;
  int bid = blockIdx.x;
  int vb = (bid & 7) * 256 + (bid >> 3);          // XCD-chunked remap (2048)
  int pb = RFL(vb * 16 + (threadIdx.x >> 6) * 4);
  const float* xw = x + (size_t)pb * HH;
  const float4* posw = reinterpret_cast<const float4*>(pos4) + pb;

  float wpe0 = Wpe[lane], wpe1 = Wpe[HH + lane], wpe2 = Wpe[2 * HH + lane];
  float wpd0 = Wpd[lane], wpd1 = Wpd[HH + lane], wpd2 = Wpd[2 * HH + lane];
  float we0 = wpe0 + wpd0, we1 = wpe1 + wpd1, we2 = wpe2 + wpd2;
  float bqq = bq[lane] + bpe[lane];
  float bkk = bk[lane] + bpe[lane] + bpd[lane];
  float bvv = bv[lane];

  float aq[4], ak[4], av[4];
#pragma unroll
  for (int p = 0; p < 4; ++p) { aq[p] = bqq; ak[p] = bkk; av[p] = bvv; }

#pragma unroll
  for (int c = 0; c < 8; ++c) {
    float wq8[8], wk8[8], wv8[8];
#pragma unroll
    for (int j = 0; j < 8; ++j) {
      int g = c * 8 + j;
      wq8[j] = Wq[g * HH + lane];
      wk8[j] = Wk[g * HH + lane];
      wv8[j] = Wv[g * HH + lane];
    }
#pragma unroll
    for (int p = 0; p < 4; ++p) {
#pragma unroll
      for (int j = 0; j < 8; ++j) {
        float xv = xw[p * HH + c * 8 + j];   // wave-uniform -> scalar load
        aq[p] = fmaf(xv, wq8[j], aq[p]);
        ak[p] = fmaf(xv, wk8[j], ak[p]);
        av[p] = fmaf(xv, wv8[j], av[p]);
      }
    }
  }

#pragma unroll
  for (int p = 0; p < 4; ++p) {
    float4 pp = posw[p];
    float qv = aq[p] + pp.x * wpe0 + pp.y * wpe1 + pp.z * wpe2;
    float kv = ak[p] + pp.x * we0 + pp.y * we1 + pp.z * we2;
    qq[(size_t)(pb + p) * HH + lane] = qv;
    reinterpret_cast<float2*>(kkv + ((size_t)(pb + p) << 7))[lane] =
        make_float2(kv, av[p]);
  }
}

// ---------------- K3: attention core — transposed multi-reduce --------------
__global__ __launch_bounds__(256) void k_attn_core(
    float* __restrict__ qq, const float* __restrict__ kkv,
    const int* __restrict__ nidx, const float* __restrict__ pos4,
    const float* __restrict__ Wpd, const float* __restrict__ Wa,
    const float* __restrict__ ba) {
  int lane = threadIdx.x & 63;
  int bid = blockIdx.x;
  int vb = (bid & 7) * 1024 + (bid >> 3);   // XCD-chunked remap (8192)
  int pu = RFL(vb * 4 + (threadIdx.x >> 6));
  int cbase = pu & ~(NPT - 1);

  float4 pp = reinterpret_cast<const float4*>(pos4)[pu];
  float u = qq[(size_t)pu * HH + lane] * Wa[lane] * 0.125f;
  float pdq = pp.x * Wpd[lane] + pp.y * Wpd[HH + lane] + pp.z * Wpd[2 * HH + lane];
  float C0 = wave_sum64(u * pdq) - ba[0];

  const int4* niw = reinterpret_cast<const int4*>(nidx + (size_t)pu * KNN_K);
  int nj[KNN_K];
#pragma unroll
  for (int g = 0; g < 4; ++g) {
    int4 r = niw[g];
    nj[g * 4 + 0] = r.x; nj[g * 4 + 1] = r.y;
    nj[g * 4 + 2] = r.z; nj[g * 4 + 3] = r.w;
  }

  float vj[KNN_K], P[KNN_K];
#pragma unroll
  for (int jj = 0; jj < KNN_K; ++jj) {
    float2 kv = reinterpret_cast<const float2*>(
        kkv + ((size_t)(cbase + nj[jj]) << 7))[lane];
    vj[jj] = kv.y;
    P[jj] = u * kv.x;
  }

  // lane l ends holding full logit for jj = l & 15
  float T = mreduce<16>(P, lane);
  float lg = T - C0;

  float mx = lg;
#pragma unroll
  for (int o = 1; o < 16; o <<= 1) mx = fmaxf(mx, __shfl_xor(mx, o, 64));
  float e = __expf(lg - mx);
  float s = e;
#pragma unroll
  for (int o = 1; o < 16; o <<= 1) s += __shfl_xor(s, o, 64);

  float oacc = 0.f;
  int sb = lane & 48;
#pragma unroll
  for (int jj = 0; jj < KNN_K; ++jj)
    oacc = fmaf(__shfl(e, sb | jj, 64), vj[jj], oacc);

  qq[(size_t)pu * HH + lane] = oacc / s;
}

// ---------------- K4: Wo GEMM + gelu + residual + LN (XCD-chunked) ----------
__global__ __launch_bounds__(256) void k_wo_ln(
    const float* __restrict__ outb, const float* __restrict__ Wo,
    const float* __restrict__ bo, float* __restrict__ x,
    const float* __restrict__ ln_s, const float* __restrict__ ln_b,
    float* __restrict__ partial, int do_pool) {
  __shared__ float red[4][HH];
  int lane = threadIdx.x & 63;
  int wv = threadIdx.x >> 6;
  int bid = blockIdx.x;
  int vb = (bid & 7) * 256 + (bid >> 3);          // XCD-chunked remap (2048)
  int pb = RFL(vb * 16 + wv * 4);
  const float* ow = outb + (size_t)pb * HH;

  float acc[4];
  float b0 = bo[lane];
#pragma unroll
  for (int p = 0; p < 4; ++p) acc[p] = b0;

#pragma unroll
  for (int c = 0; c < 8; ++c) {
    float w8[8];
#pragma unroll
    for (int j = 0; j < 8; ++j) w8[j] = Wo[(c * 8 + j) * HH + lane];
#pragma unroll
    for (int p = 0; p < 4; ++p) {
#pragma unroll
      for (int j = 0; j < 8; ++j) {
        float ov = ow[p * HH + c * 8 + j];   // wave-uniform -> scalar load
        acc[p] = fmaf(ov, w8[j], acc[p]);
      }
    }
  }

  float sg = ln_s[lane], bg = ln_b[lane];
  float xn[4];
#pragma unroll
  for (int p = 0; p < 4; ++p)
    xn[p] = x[(size_t)(pb + p) * HH + lane] + gelu_f(acc[p]);

  float Ts = mreduce<4>(xn, lane);
  float dd[4], sq[4];
#pragma unroll
  for (int p = 0; p < 4; ++p) {
    float mu = __shfl(Ts, p, 64) * (1.0f / HH);
    dd[p] = xn[p] - mu;
    sq[p] = dd[p] * dd[p];
  }
  float Tv = mreduce<4>(sq, lane);
  float mxp = -FLT_MAX;
#pragma unroll
  for (int p = 0; p < 4; ++p) {
    float var = __shfl(Tv, p, 64) * (1.0f / HH);
    float yv = dd[p] * rsqrtf(var + 1e-6f) * sg + bg;
    x[(size_t)(pb + p) * HH + lane] = yv;
    mxp = fmaxf(mxp, yv);
  }

  if (do_pool) {   // last layer: per-vblock (16-point) partial max
    red[wv][lane] = mxp;
    __syncthreads();
    if (wv == 0) {
      float m = fmaxf(fmaxf(red[0][lane], red[1][lane]),
                      fmaxf(red[2][lane], red[3][lane]));
      partial[(size_t)vb * HH + lane] = m;   // indexed by VIRTUAL block
    }
  }
}

// ---------------- K6: fused pool-finish + set-encoder + final LN + max ------
__global__ __launch_bounds__(512) void k_enc(
    const float* __restrict__ partial,
    const float* __restrict__ Wek, const float* __restrict__ bek,
    const float* __restrict__ Weq, const float* __restrict__ beq,
    const float* __restrict__ Wev, const float* __restrict__ bev,
    const float* __restrict__ We1, const float* __restrict__ be1,
    const float* __restrict__ We2, const float* __restrict__ be2,
    const float* __restrict__ ln2_s, const float* __restrict__ ln2_b,
    float* __restrict__ out) {
  __shared__ float xs[8][HH], ks[8][HH], vs[8][HH], x2[8][HH];
  int b = blockIdx.x;
  int t = threadIdx.x >> 6;     // token (cloud-in-batch) 0..7
  int h = threadIdx.x & 63;
  {
    int ci = b * 8 + t;
    const float* pp = partial + (size_t)ci * 64 * HH + h;
    float mx = pp[0];
#pragma unroll
    for (int c8 = 1; c8 < 64; ++c8) mx = fmaxf(mx, pp[c8 * HH]);
    xs[t][h] = mx;
  }
  __syncthreads();

  float kk = bek[h], qq = beq[h], vv = bev[h];
#pragma unroll 8
  for (int g = 0; g < HH; ++g) {
    float xv = xs[t][g];
    kk += xv * Wek[g * HH + h];
    qq += xv * Weq[g * HH + h];
    vv += xv * Wev[g * HH + h];
  }
  ks[t][h] = kk;
  vs[t][h] = vv;
  __syncthreads();

  float logit[8];
#pragma unroll
  for (int s = 0; s < 8; ++s) {
    float tt = qq * ks[s][h];
    logit[s] = wave_sum64(tt) * 0.125f;
  }
  float m = logit[0];
#pragma unroll
  for (int s = 1; s < 8; ++s) m = fmaxf(m, logit[s]);
  float ssum = 0.f;
#pragma unroll
  for (int s = 0; s < 8; ++s) { logit[s] = expf(logit[s] - m); ssum += logit[s]; }
  float o = 0.f;
#pragma unroll
  for (int s = 0; s < 8; ++s) o += (logit[s] / ssum) * vs[s][h];

  float h1 = be1[h];
#pragma unroll 8
  for (int g = 0; g < HH; ++g) h1 += __shfl(o, g, 64) * We1[g * HH + h];
  h1 = gelu_f(h1);
  float h2 = be2[h];
#pragma unroll 8
  for (int g = 0; g < HH; ++g) h2 += __shfl(h1, g, 64) * We2[g * HH + h];

  float xn = xs[t][h] + h2;
  float mu = wave_sum64(xn) * (1.0f / HH);
  float d = xn - mu;
  float var = wave_sum64(d * d) * (1.0f / HH);
  float yv = d * rsqrtf(var + 1e-6f) * ln2_s[h] + ln2_b[h];
  x2[t][h] = yv;
  __syncthreads();
  if (t == 0) {
    float mm = x2[0][h];
#pragma unroll
    for (int s = 1; s < 8; ++s) mm = fmaxf(mm, x2[s][h]);
    out[b * HH + h] = mm;
  }
}

// ---------------------------------------------------------------------------
extern "C" void kernel_launch(void* const* d_in, const int* in_sizes, int n_in,
                              void* d_out, int out_size, void* d_ws, size_t ws_size,
                              hipStream_t stream) {
  const float* points = (const float*)d_in[0];
  const float* w_in   = (const float*)d_in[1];
  const float* b_in   = (const float*)d_in[2];
  const float* Wq     = (const float*)d_in[3];
  const float* bq     = (const float*)d_in[4];
  const float* Wk     = (const float*)d_in[5];
  const float* bk     = (const float*)d_in[6];
  const float* Wv     = (const float*)d_in[7];
  const float* bv     = (const float*)d_in[8];
  const float* Wpe    = (const float*)d_in[9];
  const float* bpe    = (const float*)d_in[10];
  const float* Wpd    = (const float*)d_in[11];
  const float* bpd    = (const float*)d_in[12];
  const float* Wa     = (const float*)d_in[13];
  const float* ba     = (const float*)d_in[14];
  const float* Wo     = (const float*)d_in[15];
  const float* bo     = (const float*)d_in[16];
  const float* ln_s   = (const float*)d_in[17];
  const float* ln_b   = (const float*)d_in[18];
  const float* Wek    = (const float*)d_in[19];
  const float* bek    = (const float*)d_in[20];
  const float* Weq    = (const float*)d_in[21];
  const float* beq    = (const float*)d_in[22];
  const float* Wev    = (const float*)d_in[23];
  const float* bev    = (const float*)d_in[24];
  const float* We1    = (const float*)d_in[25];
  const float* be1    = (const float*)d_in[26];
  const float* We2    = (const float*)d_in[27];
  const float* be2    = (const float*)d_in[28];
  const float* ln2_s  = (const float*)d_in[29];
  const float* ln2_b  = (const float*)d_in[30];

  float* ws      = (float*)d_ws;
  float* pos4    = ws;                      // 4*PTOT
  float* xbuf    = pos4 + 4 * PTOT;         // 64*PTOT
  float* qbuf    = xbuf + 64 * PTOT;        // 64*PTOT (qq, then attn-out)
  float* kkv     = qbuf + 64 * PTOT;        // 128*PTOT (kk,v interleaved)
  float* partial = kkv + 128 * PTOT;        // 2048*HH
  int*   nidx    = (int*)(partial + 2048 * HH);  // 16*PTOT ints

  k_front<<<KNN_BLKS + PTOT / 4, 256, 0, stream>>>(points, w_in, b_in,
                                                   xbuf, pos4, nidx);

  for (int l = 0; l < 3; ++l) {
    k_qkv_gemm<<<PTOT / 16, 256, 0, stream>>>(xbuf, pos4,
        Wq + l * HH * HH, bq + l * HH,
        Wk + l * HH * HH, bk + l * HH,
        Wv + l * HH * HH, bv + l * HH,
        Wpe + l * 3 * HH, bpe + l * HH,
        Wpd + l * 3 * HH, bpd + l * HH,
        qbuf, kkv);
    k_attn_core<<<PTOT / 4, 256, 0, stream>>>(qbuf, kkv, nidx, pos4,
        Wpd + l * 3 * HH, Wa + l * HH, ba + l);
    k_wo_ln<<<PTOT / 16, 256, 0, stream>>>(qbuf,
        Wo + l * HH * HH, bo + l * HH, xbuf,
        ln_s + l * HH, ln_b + l * HH, partial, l == 2 ? 1 : 0);
  }

  k_enc<<<4, 512, 0, stream>>>(partial, Wek, bek, Weq, beq, Wev, bev,
                               We1, be1, We2, be2, ln2_s, ln2_b, (float*)d_out);
}